// Round 6
// baseline (122.637 us; speedup 1.0000x reference)
//
#include <hip/hip_runtime.h>
#include <hip/hip_bf16.h>

// Fixed problem sizes (setup_inputs): B=8, T1=32768, M=16384, T2=131072,
// TT=163840 tokens/batch, C=32, O=256, out rows/batch NU=4096.
// Algebraic collapse: Out = Ind[rows x 128] @ T[128 x 256] via bf16 MFMA.
//
// R6 = MEASUREMENT ROUND 2: fused's core is ~29us by subtraction (R5 probe:
// prep+oh = 5.3us; floor ~65.5us anchored by R1 rocprof) but static model
// says ~8-10us, and fused never appears in the top-5 table (masked by 43us
// ws-poison fills). This round REPLICATES the full fused body 6x inside the
// kernel (idempotent, trip count is a runtime arg) so the dispatch runs
// ~170us and surfaces with full counters (MfmaUtil/VALUBusy/Occupancy/LDS
// conflicts/FETCH/WRITE) for a profile-guided R7 rewrite.

typedef short short8 __attribute__((ext_vector_type(8)));
typedef float f32x4 __attribute__((ext_vector_type(4)));

constexpr int TT_TOT = 163840;
constexpr int T1     = 32768;
constexpr int NU     = 4096;

// ---------------- prep: 256 blocks (one per o), LDS-staged ----------------
__global__ __launch_bounds__(256) void prep_kernel(
    const float* __restrict__ emb1, const float* __restrict__ emb2,
    const float* __restrict__ W1,   const float* __restrict__ b1,
    const float* __restrict__ W2,   const float* __restrict__ b2,
    unsigned short* __restrict__ Tt)
{
    __shared__ float W2L[256 * 33];
    __shared__ float P[24 * 33];
    __shared__ float Wrow[256];
    __shared__ float E1[128], E2[128], B2[32];
    const int t = threadIdx.x;
    const int o = blockIdx.x;

    {
        #pragma unroll
        for (int c = 0; c < 32; ++c)
            W2L[t * 33 + c] = W2[c * 256 + t];
    }
    Wrow[t] = W1[o * 256 + t];
    if (t < 128) E1[t] = emb1[t];
    if (t >= 128 && t < 256) E2[t - 128] = emb2[t - 128];
    if (t < 32) B2[t] = b2[t];
    __syncthreads();

    #pragma unroll
    for (int i = 0; i < 3; ++i) {
        int idx = t + i * 256;
        int r = idx >> 5, c = idx & 31;
        int v1 = r >> 3, j = r & 7;
        float s = 0.f;
        #pragma unroll
        for (int cp = 0; cp < 32; ++cp)
            s += E2[(v1 + 1) * 32 + cp] * W2L[(cp * 8 + j) * 33 + c];
        P[r * 33 + c] = s;
    }
    __syncthreads();

    if (t < 128) {
        const int kap = t;
        float val = 0.f;
        if (kap < 96) {
            int v1 = kap >> 5, j = (kap >> 2) & 7, kk = kap & 3;
            #pragma unroll
            for (int c = 0; c < 32; ++c)
                val += P[(v1 * 8 + j) * 33 + c] * Wrow[c * 8 + 2 * kk];
        } else if (kap < 108) {
            int q = kap - 96; int v1 = q >> 2, ko = q & 3;
            #pragma unroll
            for (int c = 0; c < 32; ++c)
                val += E1[(v1 + 1) * 32 + c] * Wrow[c * 8 + 2 * ko + 1];
        } else if (kap == 108) {
            val = b1[o];
            #pragma unroll
            for (int kk = 0; kk < 4; ++kk)
                #pragma unroll
                for (int c = 0; c < 32; ++c)
                    val += B2[c] * Wrow[c * 8 + 2 * kk];
        }
        __hip_bfloat16 h = __float2bfloat16(val);
        Tt[o * 128 + kap] = *reinterpret_cast<unsigned short*>(&h);
    }
}

// ---------------- main: identical to R4 but body repeated `reps` times -----
__global__ __launch_bounds__(256) void fused_kernel(
    const int* __restrict__ value,
    const unsigned short* __restrict__ Tt,
    float* __restrict__ out,
    int reps)
{
    __shared__ unsigned short Ind[64 * 128];   // 16 KB
    const int t  = threadIdx.x;
    const int b  = blockIdx.x >> 6;
    const int u0 = (blockIdx.x & 63) * 64;
    const int lane = t & 63, w = t >> 6;
    const int m = lane & 15, quad = lane >> 4;

    for (int rep = 0; rep < reps; ++rep) {
        // zero the indicator tile
        #pragma unroll
        for (int i = 0; i < 4; ++i)
            ((uint4*)Ind)[t + i * 256] = make_uint4(0u, 0u, 0u, 0u);

        // T fragments: lane&15 -> o within 16-tile, quad*8+j -> kappa
        short8 tfrag[4][4];
        #pragma unroll
        for (int ot = 0; ot < 4; ++ot)
            #pragma unroll
            for (int ks = 0; ks < 4; ++ks)
                tfrag[ot][ks] = *(const short8*)(Tt + (w * 64 + ot * 16 + m) * 128
                                                    + ks * 32 + quad * 8);

        __syncthreads();

        // scatter: thread (row = t&63, q = t>>6) handles kk=q of its row
        {
            const int row = t & 63, q = t >> 6;
            const int u   = u0 + row;
            const int* vb = value + b * TT_TOT;
            const int* tok = vb + T1 + u * 32 + q * 8;
            int4 ta  = *(const int4*)tok;
            int4 tb2 = *(const int4*)(tok + 4);
            int vj[8] = {ta.x, ta.y, ta.z, ta.w, tb2.x, tb2.y, tb2.z, tb2.w};
            unsigned short* Ir = Ind + row * 128;
            const int rx = row & 7;
            #pragma unroll
            for (int j = 0; j < 8; ++j) {
                int v = vj[j];
                if (v > 0) {
                    int slot = (v - 1) * 32 + j * 4 + q;
                    Ir[(((slot >> 3) ^ rx) << 3) + (slot & 7)] = 0x3F80;
                }
            }
            int v1 = vb[u * 8 + 2 * q + 1];
            if (v1 > 0) {
                int slot = 96 + (v1 - 1) * 4 + q;
                Ir[(((slot >> 3) ^ rx) << 3) + (slot & 7)] = 0x3F80;
            }
            if (q == 0) {
                int slot = 108;
                Ir[(((slot >> 3) ^ rx) << 3) + (slot & 7)] = 0x3F80;
            }
        }
        __syncthreads();

        // MFMA: wave w owns o-tiles [w*64, w*64+64) (M); u-tiles are N
        f32x4 acc[4][4] = {};
        #pragma unroll
        for (int ut = 0; ut < 4; ++ut) {
            const int rl = ut * 16 + m;
            short8 ifrag[4];
            #pragma unroll
            for (int ks = 0; ks < 4; ++ks)
                ifrag[ks] = *(const short8*)&Ind[rl * 128 +
                                  (((ks * 4 + quad) ^ (m & 7)) << 3)];
            #pragma unroll
            for (int ot = 0; ot < 4; ++ot)
                #pragma unroll
                for (int ks = 0; ks < 4; ++ks)
                    acc[ot][ut] = __builtin_amdgcn_mfma_f32_16x16x32_bf16(
                        tfrag[ot][ks], ifrag[ks], acc[ot][ut], 0, 0, 0);
        }

        // store: lane's 4 regs = 4 consecutive o -> dwordx4
        #pragma unroll
        for (int ut = 0; ut < 4; ++ut) {
            const int u = u0 + ut * 16 + m;
            #pragma unroll
            for (int ot = 0; ot < 4; ++ot) {
                float* op = out + ((b * NU + u) * 256) + w * 64 + ot * 16 + quad * 4;
                *(f32x4*)op = acc[ot][ut];
            }
        }
        __syncthreads();   // protect Ind before next rep's re-zero
    }
}

extern "C" void kernel_launch(void* const* d_in, const int* in_sizes, int n_in,
                              void* d_out, int out_size, void* d_ws, size_t ws_size,
                              hipStream_t stream)
{
    const int*   value = (const int*)  d_in[0];
    const float* emb1  = (const float*)d_in[3];
    const float* emb2  = (const float*)d_in[4];
    const float* W1    = (const float*)d_in[5];
    const float* b1    = (const float*)d_in[6];
    const float* W2    = (const float*)d_in[7];
    const float* b2    = (const float*)d_in[8];
    float* out = (float*)d_out;

    unsigned short* Tt = (unsigned short*)d_ws;   // 256*128 bf16 = 64 KB

    prep_kernel<<<256, 256, 0, stream>>>(emb1, emb2, W1, b1, W2, b2, Tt);
    // MEASUREMENT: 6 identical internal reps -> fused dispatch ~6x longer,
    // surfaces in top-5 with full counters. Revert reps to 1 in R7.
    fused_kernel<<<512, 256, 0, stream>>>(value, Tt, out, 6);
}

// Round 7
// 103.792 us; speedup vs baseline: 1.1816x; 1.1816x over previous
//
#include <hip/hip_runtime.h>
#include <hip/hip_bf16.h>

// Fixed problem sizes (setup_inputs): B=8, T1=32768, M=16384, T2=131072,
// TT=163840 tokens/batch, C=32, O=256, out rows/batch NU=4096.
// Algebraic collapse: Out = Ind[rows x 128] @ T[128 x 256] via bf16 MFMA
// (T precomputed by prep; Ind is a 0/1 token-indicator, exact in bf16).
//
// R7: measured split (R5/R6 probes): harness floor ~88us, prep+oh 5.3us,
// fused core 4.6us. fused is a latency chain at 2 blocks/CU (output is
// L3-absorbed, MFMA ~0.3us -> neither matters). This round: 32-row tiles
// (1024 blocks, 8KB LDS -> 3-4 blocks/CU overlap) + token HBM loads issued
// before anything else.

typedef short short8 __attribute__((ext_vector_type(8)));
typedef float f32x4 __attribute__((ext_vector_type(4)));

constexpr int TT_TOT = 163840;
constexpr int T1     = 32768;
constexpr int NU     = 4096;

// ---------------- prep: 256 blocks (one per o), LDS-staged ----------------
// kappa layout: 0..95  : ((v-1)*8+j)*4+kk  -> R[v][j][kk][o]
//               96..107: 96+(v-1)*4+ko     -> Q[v][ko][o]
//               108    : bias[o],  109..127: 0
__global__ __launch_bounds__(256) void prep_kernel(
    const float* __restrict__ emb1, const float* __restrict__ emb2,
    const float* __restrict__ W1,   const float* __restrict__ b1,
    const float* __restrict__ W2,   const float* __restrict__ b2,
    unsigned short* __restrict__ Tt)
{
    __shared__ float W2L[256 * 33];
    __shared__ float P[24 * 33];
    __shared__ float Wrow[256];
    __shared__ float E1[128], E2[128], B2[32];
    const int t = threadIdx.x;
    const int o = blockIdx.x;

    {
        #pragma unroll
        for (int c = 0; c < 32; ++c)
            W2L[t * 33 + c] = W2[c * 256 + t];
    }
    Wrow[t] = W1[o * 256 + t];
    if (t < 128) E1[t] = emb1[t];
    if (t >= 128 && t < 256) E2[t - 128] = emb2[t - 128];
    if (t < 32) B2[t] = b2[t];
    __syncthreads();

    #pragma unroll
    for (int i = 0; i < 3; ++i) {
        int idx = t + i * 256;
        int r = idx >> 5, c = idx & 31;
        int v1 = r >> 3, j = r & 7;
        float s = 0.f;
        #pragma unroll
        for (int cp = 0; cp < 32; ++cp)
            s += E2[(v1 + 1) * 32 + cp] * W2L[(cp * 8 + j) * 33 + c];
        P[r * 33 + c] = s;
    }
    __syncthreads();

    if (t < 128) {
        const int kap = t;
        float val = 0.f;
        if (kap < 96) {
            int v1 = kap >> 5, j = (kap >> 2) & 7, kk = kap & 3;
            #pragma unroll
            for (int c = 0; c < 32; ++c)
                val += P[(v1 * 8 + j) * 33 + c] * Wrow[c * 8 + 2 * kk];
        } else if (kap < 108) {
            int q = kap - 96; int v1 = q >> 2, ko = q & 3;
            #pragma unroll
            for (int c = 0; c < 32; ++c)
                val += E1[(v1 + 1) * 32 + c] * Wrow[c * 8 + 2 * ko + 1];
        } else if (kap == 108) {
            val = b1[o];
            #pragma unroll
            for (int kk = 0; kk < 4; ++kk)
                #pragma unroll
                for (int c = 0; c < 32; ++c)
                    val += B2[c] * Wrow[c * 8 + 2 * kk];
        }
        __hip_bfloat16 h = __float2bfloat16(val);
        Tt[o * 128 + kap] = *reinterpret_cast<unsigned short*>(&h);
    }
}

// ---------------- main: 32-row x 256-o tile per block, 1024 blocks ---------
// Ind in LDS: [32 rows][128 kappa] bf16, 16-B chunks XOR-swizzled by (row&7).
// 8 threads per row: j8<4 scatter R-slots (kk=j8), j8>=4 the Q-slot (ko=j8-4),
// j8==4 also the bias slot.
__global__ __launch_bounds__(256) void fused_kernel(
    const int* __restrict__ value,
    const unsigned short* __restrict__ Tt,
    float* __restrict__ out)
{
    __shared__ unsigned short Ind[32 * 128];   // 8 KB
    const int t  = threadIdx.x;
    const int b  = blockIdx.x >> 7;
    const int u0 = (blockIdx.x & 127) * 32;
    const int lane = t & 63, w = t >> 6;
    const int m = lane & 15, quad = lane >> 4;
    const int row = t & 31, j8 = t >> 5;
    const int u = u0 + row;
    const int* vb = value + b * TT_TOT;

    // 1) token loads FIRST (HBM latency starts now)
    int4 ta = {0,0,0,0}, tb2 = {0,0,0,0};
    int v1tok = 0;
    if (j8 < 4) {
        const int* tok = vb + T1 + u * 32 + j8 * 8;
        ta  = *(const int4*)tok;
        tb2 = *(const int4*)(tok + 4);
    } else {
        v1tok = vb[u * 8 + 2 * (j8 - 4) + 1];
    }

    // 2) T fragments (L1/L2-hot: whole Tt is 64 KB, reused by all blocks)
    short8 tfrag[4][4];
    #pragma unroll
    for (int ot = 0; ot < 4; ++ot)
        #pragma unroll
        for (int ks = 0; ks < 4; ++ks)
            tfrag[ot][ks] = *(const short8*)(Tt + (w * 64 + ot * 16 + m) * 128
                                                + ks * 32 + quad * 8);

    // 3) zero the indicator tile (8 KB / 256 threads = 2 uint4 each)
    ((uint4*)Ind)[t]       = make_uint4(0u, 0u, 0u, 0u);
    ((uint4*)Ind)[t + 256] = make_uint4(0u, 0u, 0u, 0u);
    __syncthreads();

    // 4) scatter
    {
        unsigned short* Ir = Ind + row * 128;
        const int rx = row & 7;
        if (j8 < 4) {
            int vj[8] = {ta.x, ta.y, ta.z, ta.w, tb2.x, tb2.y, tb2.z, tb2.w};
            #pragma unroll
            for (int j = 0; j < 8; ++j) {
                int v = vj[j];
                if (v > 0) {
                    int slot = (v - 1) * 32 + j * 4 + j8;
                    Ir[(((slot >> 3) ^ rx) << 3) + (slot & 7)] = 0x3F80;
                }
            }
        } else {
            if (v1tok > 0) {
                int slot = 96 + (v1tok - 1) * 4 + (j8 - 4);
                Ir[(((slot >> 3) ^ rx) << 3) + (slot & 7)] = 0x3F80;
            }
            if (j8 == 4) {
                int slot = 108;                // bias always on
                Ir[(((slot >> 3) ^ rx) << 3) + (slot & 7)] = 0x3F80;
            }
        }
    }
    __syncthreads();

    // 5) MFMA: wave w owns o-tiles [w*64, w*64+64) (M); 2 u-tiles (N), K=128
    f32x4 acc[4][2] = {};
    #pragma unroll
    for (int ut = 0; ut < 2; ++ut) {
        const int rl = ut * 16 + m;
        short8 ifrag[4];
        #pragma unroll
        for (int ks = 0; ks < 4; ++ks)
            ifrag[ks] = *(const short8*)&Ind[rl * 128 +
                              (((ks * 4 + quad) ^ (m & 7)) << 3)];
        #pragma unroll
        for (int ot = 0; ot < 4; ++ot)
            #pragma unroll
            for (int ks = 0; ks < 4; ++ks)
                acc[ot][ut] = __builtin_amdgcn_mfma_f32_16x16x32_bf16(
                    tfrag[ot][ks], ifrag[ks], acc[ot][ut], 0, 0, 0);
    }

    // 6) store: lane's 4 regs = 4 consecutive o -> dwordx4
    #pragma unroll
    for (int ut = 0; ut < 2; ++ut) {
        const int us = u0 + ut * 16 + m;
        #pragma unroll
        for (int ot = 0; ot < 4; ++ot) {
            float* op = out + ((b * NU + us) * 256) + w * 64 + ot * 16 + quad * 4;
            *(f32x4*)op = acc[ot][ut];
        }
    }
}

extern "C" void kernel_launch(void* const* d_in, const int* in_sizes, int n_in,
                              void* d_out, int out_size, void* d_ws, size_t ws_size,
                              hipStream_t stream)
{
    const int*   value = (const int*)  d_in[0];
    const float* emb1  = (const float*)d_in[3];
    const float* emb2  = (const float*)d_in[4];
    const float* W1    = (const float*)d_in[5];
    const float* b1    = (const float*)d_in[6];
    const float* W2    = (const float*)d_in[7];
    const float* b2    = (const float*)d_in[8];
    float* out = (float*)d_out;

    unsigned short* Tt = (unsigned short*)d_ws;   // 256*128 bf16 = 64 KB

    prep_kernel<<<256, 256, 0, stream>>>(emb1, emb2, W1, b1, W2, b2, Tt);
    fused_kernel<<<1024, 256, 0, stream>>>(value, Tt, out);
}

// Round 8
// 101.916 us; speedup vs baseline: 1.2033x; 1.0184x over previous
//
#include <hip/hip_runtime.h>
#include <hip/hip_bf16.h>

// Fixed problem sizes (setup_inputs): B=8, T1=32768, M=16384, T2=131072,
// TT=163840 tokens/batch, C=32, O=256, out rows/batch NU=4096.
// Algebraic collapse: Out = Ind[rows x 128] @ T[128 x 256] via bf16 MFMA
// (T precomputed by prep; Ind is a 0/1 token-indicator, exact in bf16).
//
// R8: REVERT to R4's 64-row/512-block fused (R7's 32-row tiling regressed:
// per-block cost is dominated by the fixed 64KB Tt fragment read, so fewer
// rows/block = double Tt L2 traffic for half the amortizing MFMA). Keep
// R7's one good idea: token HBM loads issued at the very top (~900-cycle
// latency starts before tfrag/zero work).
// Measured split (R5/R6 probes): harness floor ~88us (poison fills at
// 76-79% HBM peak), prep ~2.5us, fused ~4.6us, 2 dispatch overheads.

typedef short short8 __attribute__((ext_vector_type(8)));
typedef float f32x4 __attribute__((ext_vector_type(4)));

constexpr int TT_TOT = 163840;
constexpr int T1     = 32768;
constexpr int NU     = 4096;

// ---------------- prep: 256 blocks (one per o), LDS-staged ----------------
// kappa layout: 0..95  : ((v-1)*8+j)*4+kk  -> R[v][j][kk][o]
//               96..107: 96+(v-1)*4+ko     -> Q[v][ko][o]
//               108    : bias[o],  109..127: 0
__global__ __launch_bounds__(256) void prep_kernel(
    const float* __restrict__ emb1, const float* __restrict__ emb2,
    const float* __restrict__ W1,   const float* __restrict__ b1,
    const float* __restrict__ W2,   const float* __restrict__ b2,
    unsigned short* __restrict__ Tt)
{
    __shared__ float W2L[256 * 33];
    __shared__ float P[24 * 33];
    __shared__ float Wrow[256];
    __shared__ float E1[128], E2[128], B2[32];
    const int t = threadIdx.x;
    const int o = blockIdx.x;

    {
        #pragma unroll
        for (int c = 0; c < 32; ++c)
            W2L[t * 33 + c] = W2[c * 256 + t];
    }
    Wrow[t] = W1[o * 256 + t];
    if (t < 128) E1[t] = emb1[t];
    if (t >= 128 && t < 256) E2[t - 128] = emb2[t - 128];
    if (t < 32) B2[t] = b2[t];
    __syncthreads();

    #pragma unroll
    for (int i = 0; i < 3; ++i) {
        int idx = t + i * 256;
        int r = idx >> 5, c = idx & 31;
        int v1 = r >> 3, j = r & 7;
        float s = 0.f;
        #pragma unroll
        for (int cp = 0; cp < 32; ++cp)
            s += E2[(v1 + 1) * 32 + cp] * W2L[(cp * 8 + j) * 33 + c];
        P[r * 33 + c] = s;
    }
    __syncthreads();

    if (t < 128) {
        const int kap = t;
        float val = 0.f;
        if (kap < 96) {
            int v1 = kap >> 5, j = (kap >> 2) & 7, kk = kap & 3;
            #pragma unroll
            for (int c = 0; c < 32; ++c)
                val += P[(v1 * 8 + j) * 33 + c] * Wrow[c * 8 + 2 * kk];
        } else if (kap < 108) {
            int q = kap - 96; int v1 = q >> 2, ko = q & 3;
            #pragma unroll
            for (int c = 0; c < 32; ++c)
                val += E1[(v1 + 1) * 32 + c] * Wrow[c * 8 + 2 * ko + 1];
        } else if (kap == 108) {
            val = b1[o];
            #pragma unroll
            for (int kk = 0; kk < 4; ++kk)
                #pragma unroll
                for (int c = 0; c < 32; ++c)
                    val += B2[c] * Wrow[c * 8 + 2 * kk];
        }
        __hip_bfloat16 h = __float2bfloat16(val);
        Tt[o * 128 + kap] = *reinterpret_cast<unsigned short*>(&h);
    }
}

// ---------------- main: Out tile (64 rows x 256 o) per block, 512 blocks ---
// Ind in LDS: [64 rows][128 kappa] bf16, 16-B chunks XOR-swizzled by (row&7)
// so the per-row ds_read_b128s are bank-conflict-free.
__global__ __launch_bounds__(256) void fused_kernel(
    const int* __restrict__ value,
    const unsigned short* __restrict__ Tt,
    float* __restrict__ out)
{
    __shared__ unsigned short Ind[64 * 128];   // 16 KB
    const int t  = threadIdx.x;
    const int b  = blockIdx.x >> 6;
    const int u0 = (blockIdx.x & 63) * 64;
    const int lane = t & 63, w = t >> 6;
    const int m = lane & 15, quad = lane >> 4;
    const int row = t & 63, q = t >> 6;
    const int u = u0 + row;
    const int* vb = value + b * TT_TOT;

    // 1) token HBM loads FIRST (latency starts before anything else)
    const int* tok = vb + T1 + u * 32 + q * 8;
    const int4 ta  = *(const int4*)tok;
    const int4 tb2 = *(const int4*)(tok + 4);
    const int  v1tok = vb[u * 8 + 2 * q + 1];

    // 2) T fragments (L2-hot: whole Tt is 64 KB, reused by every block)
    short8 tfrag[4][4];
    #pragma unroll
    for (int ot = 0; ot < 4; ++ot)
        #pragma unroll
        for (int ks = 0; ks < 4; ++ks)
            tfrag[ot][ks] = *(const short8*)(Tt + (w * 64 + ot * 16 + m) * 128
                                                + ks * 32 + quad * 8);

    // 3) zero the indicator tile
    #pragma unroll
    for (int i = 0; i < 4; ++i)
        ((uint4*)Ind)[t + i * 256] = make_uint4(0u, 0u, 0u, 0u);
    __syncthreads();

    // 4) scatter: thread (row, q) handles kk=q of its row
    {
        int vj[8] = {ta.x, ta.y, ta.z, ta.w, tb2.x, tb2.y, tb2.z, tb2.w};
        unsigned short* Ir = Ind + row * 128;
        const int rx = row & 7;
        #pragma unroll
        for (int j = 0; j < 8; ++j) {
            int v = vj[j];
            if (v > 0) {
                int slot = (v - 1) * 32 + j * 4 + q;
                Ir[(((slot >> 3) ^ rx) << 3) + (slot & 7)] = 0x3F80;
            }
        }
        if (v1tok > 0) {
            int slot = 96 + (v1tok - 1) * 4 + q;
            Ir[(((slot >> 3) ^ rx) << 3) + (slot & 7)] = 0x3F80;
        }
        if (q == 0) {
            int slot = 108;                   // bias always on
            Ir[(((slot >> 3) ^ rx) << 3) + (slot & 7)] = 0x3F80;
        }
    }
    __syncthreads();

    // 5) MFMA: wave w owns o-tiles [w*64, w*64+64) (M); u-tiles are N, K=128
    f32x4 acc[4][4] = {};
    #pragma unroll
    for (int ut = 0; ut < 4; ++ut) {
        const int rl = ut * 16 + m;
        short8 ifrag[4];
        #pragma unroll
        for (int ks = 0; ks < 4; ++ks)
            ifrag[ks] = *(const short8*)&Ind[rl * 128 +
                              (((ks * 4 + quad) ^ (m & 7)) << 3)];
        #pragma unroll
        for (int ot = 0; ot < 4; ++ot)
            #pragma unroll
            for (int ks = 0; ks < 4; ++ks)
                acc[ot][ut] = __builtin_amdgcn_mfma_f32_16x16x32_bf16(
                    tfrag[ot][ks], ifrag[ks], acc[ot][ut], 0, 0, 0);
    }

    // 6) store: lane's 4 regs = 4 consecutive o -> dwordx4
    #pragma unroll
    for (int ut = 0; ut < 4; ++ut) {
        const int us = u0 + ut * 16 + m;
        #pragma unroll
        for (int ot = 0; ot < 4; ++ot) {
            float* op = out + ((b * NU + us) * 256) + w * 64 + ot * 16 + quad * 4;
            *(f32x4*)op = acc[ot][ut];
        }
    }
}

extern "C" void kernel_launch(void* const* d_in, const int* in_sizes, int n_in,
                              void* d_out, int out_size, void* d_ws, size_t ws_size,
                              hipStream_t stream)
{
    const int*   value = (const int*)  d_in[0];
    const float* emb1  = (const float*)d_in[3];
    const float* emb2  = (const float*)d_in[4];
    const float* W1    = (const float*)d_in[5];
    const float* b1    = (const float*)d_in[6];
    const float* W2    = (const float*)d_in[7];
    const float* b2    = (const float*)d_in[8];
    float* out = (float*)d_out;

    unsigned short* Tt = (unsigned short*)d_ws;   // 256*128 bf16 = 64 KB

    prep_kernel<<<256, 256, 0, stream>>>(emb1, emb2, W1, b1, W2, b2, Tt);
    fused_kernel<<<512, 256, 0, stream>>>(value, Tt, out);
}